// Round 7
// baseline (323.703 us; speedup 1.0000x reference)
//
#include <hip/hip_runtime.h>
#include <math.h>

#define NUM_CLASSES 27
#define HDIM 256
#define WDIM 256
#define NPIX (HDIM * WDIM)

// Fixed problem shape: B=16, M=32, H=W=256.
// 256-thread blocks: hist LDS = 28*256*4 = 28.7 KB -> ~5 blocks/CU co-resident
#define NB_HIST 512              // B*M blocks, one per (b,m)
#define NB_BND 1024              // B*HDIM/4 blocks, 4 rows each (1 row/wave)
#define ROWS_PER_BND_BLOCK 4

// ws layout (floats), all slots written every launch (no zeroing needed):
//   ws[0    .. 512)  : entropy per (b,m) block
//   ws[512  .. 1536) : intersection per boundary block (1024)
//   ws[1536 .. 2560) : union per boundary block (1024)
//   ws[2560 .. 3584) : dbc-term sum per boundary block (1024)
//
// Post-mortem ledger (do not regress):
//  - R1: atomicAdd on LDS float -> strict-IEEE CAS-loop fallback, 3x regression.
//  - R2: single-kernel finalize via per-block agent-scope ACQ_REL fetch_add ->
//    per-block L2 cache ops, 2.5x regression. Two-kernel form keeps the free
//    kernel-boundary release/acquire.
//  - R4/R5: __hip_atomic_fetch_add(WORKGROUP) on LDS -> container failed twice
//    (likely same CAS-loop lowering). Construct banned.
//  - R6: 4-chunk hist split (2048 blocks) -> +12us REGRESSION: per-block fixed
//    costs (LDS zero-init, stage-2, launch) quadrupled and exceeded the
//    latency-hiding gain. R3 structure (512 hist blocks, nch=1) is the best
//    measured baseline (202.4 us).
//  - R7: attack the RMW chain with unsafeAtomicAdd -> hardware ds_add_f32
//    (no-return, fire-and-forget, no CAS). Bit-identical: operands never
//    denormal, DS pipe in-order per wave, single owner per address.

__global__ __launch_bounds__(256) void fused_kernel(
    const float* __restrict__ masks, const int* __restrict__ sem,
    const float* __restrict__ depth, float* __restrict__ ws, int M) {
  // Conflict-free layout: bin c of thread t at s_hist[c][t].
  // Row stride = 256 floats (== 0 mod 32 banks), so bank = t & 31:
  // class-independent, exactly 2 lanes/bank per wave access -> free (m136).
  __shared__ float s_hist[28][256];  // 28.7 KB
  __shared__ float s_part[8][32];
  __shared__ float s_i[4], s_u[4], s_t[4];

  const int tid = threadIdx.x;

  if (blockIdx.x < NB_HIST) {
    // ---------------- histogram + entropy for one (b,m) ----------------
    const int bm = blockIdx.x;
    const int b = bm / M;
    const int m = bm % M;

#pragma unroll
    for (int c = 0; c < 28; ++c) s_hist[c][tid] = 0.0f;
    // no sync needed: hot loop touches only this thread's own column

    const float4* __restrict__ m4 =
        (const float4*)(masks + ((size_t)b * M + m) * (size_t)NPIX);
    const int4* __restrict__ s4 = (const int4*)(sem + (size_t)b * (size_t)NPIX);

    const int iters = NPIX / 4 / 256;  // 64
#pragma unroll 4
    for (int it = 0; it < iters; ++it) {
      const int idx = it * 256 + tid;
      const float4 mv = m4[idx];
      const int4 cv = s4[idx];
      // unsafeAtomicAdd -> ds_add_f32 (no-rtn): removes the 256-deep
      // ds_read->wait->add->ds_write serial chain of the `+=` form.
      unsafeAtomicAdd(&s_hist[cv.x][tid], mv.x);
      unsafeAtomicAdd(&s_hist[cv.y][tid], mv.y);
      unsafeAtomicAdd(&s_hist[cv.z][tid], mv.z);
      unsafeAtomicAdd(&s_hist[cv.w][tid], mv.w);
    }
    __syncthreads();

    // stage 2: thread (c = tid&31, s = tid>>5) sums bin c over 32 columns.
    // Skew iteration by c so banks stay spread (2-way only).
    {
      const int c = tid & 31;
      const int s = tid >> 5;  // 8 groups of 32 columns
      if (c < 28) {
        float acc = 0.f;
#pragma unroll
        for (int i = 0; i < 32; ++i)
          acc += s_hist[c][s * 32 + ((i + c) & 31)];
        s_part[s][c] = acc;
      }
    }
    __syncthreads();

    // stage 3: one wave finishes
    if (tid < 64) {
      float tot = 0.f;
      if (tid < 28) {
#pragma unroll
        for (int g = 0; g < 8; ++g) tot += s_part[g][tid];
      }
      float ms = tot;  // sum of all bins == sum over n of mask
      for (int off = 32; off > 0; off >>= 1) ms += __shfl_xor(ms, off);
      ms += 1e-6f;
      float ent = 0.f;
      if (tid < NUM_CLASSES) {
        float p = fminf(fmaxf(tot / ms, 1e-7f), 1.0f);
        if (p > 1e-6f) ent = p * logf(p + 1e-10f);
      }
      for (int off = 32; off > 0; off >>= 1) ent += __shfl_xor(ent, off);
      if (tid == 0) ws[bm] = -ent;
    }
  } else {
    // ---------------- boundary IoU + depth coherence: 4 rows/block ----------------
    const int j = blockIdx.x - NB_HIST;
    const int wave = tid >> 6;
    const int lane = tid & 63;
    const int brow = j * ROWS_PER_BND_BLOCK + wave;  // all 4 rows share b
    const int b = brow >> 8;
    const int y = brow & 255;

    const size_t rowoff = (size_t)b * NPIX + (size_t)y * WDIM;
    const float4* mp = (const float4*)(masks + (size_t)b * M * NPIX + (size_t)y * WDIM);
    const float4* dp = (const float4*)(depth + rowoff);
    const int4* sp = (const int4*)(sem + rowoff);

    const int uoff = (y > 0) ? -(WDIM / 4) : 0;

    const float4 mv = mp[lane];
    const float4 mvu = mp[lane + uoff];
    const float4 dv = dp[lane];
    const float4 dvu = dp[lane + uoff];
    const int4 sv = sp[lane];
    const int4 svu = sp[lane + uoff];

    const int src = (lane > 0) ? (lane - 1) : 0;
    float mw = __shfl(mv.w, src);
    float dw = __shfl(dv.w, src);
    int swv = __shfl(sv.w, src);
    if (lane == 0) { mw = mv.x; dw = dv.x; swv = sv.x; }

    const float ml[4] = {mw, mv.x, mv.y, mv.z};
    const float dl[4] = {dw, dv.x, dv.y, dv.z};
    const int sl[4] = {swv, sv.x, sv.y, sv.z};
    const float mc[4] = {mv.x, mv.y, mv.z, mv.w};
    const float dc[4] = {dv.x, dv.y, dv.z, dv.w};
    const int sc[4] = {sv.x, sv.y, sv.z, sv.w};
    const float mu[4] = {mvu.x, mvu.y, mvu.z, mvu.w};
    const float du[4] = {dvu.x, dvu.y, dvu.z, dvu.w};
    const int su[4] = {svu.x, svu.y, svu.z, svu.w};

    float inter = 0.f, uni = 0.f, term = 0.f;
#pragma unroll
    for (int k = 0; k < 4; ++k) {
      const bool semb = (sc[k] != sl[k]) || (sc[k] != su[k]);
      const bool instb = (fabsf(mc[k] - ml[k]) > 0.3f) || (fabsf(mc[k] - mu[k]) > 0.3f);
      inter += (semb && instb) ? 1.0f : 0.0f;
      uni += (semb || instb) ? 1.0f : 0.0f;
      const float gx = dc[k] - dl[k];
      const float gy = dc[k] - du[k];
      const float db = sqrtf(fmaxf(gx * gx + gy * gy, 1e-24f));
      const float dbc = fminf(db, 2.0f);
      term += semb ? 0.0f : (1.0f + 3.0f * dbc) * dbc;
    }

    for (int off = 32; off > 0; off >>= 1) {
      inter += __shfl_down(inter, off);
      uni += __shfl_down(uni, off);
      term += __shfl_down(term, off);
    }
    if (lane == 0) { s_i[wave] = inter; s_u[wave] = uni; s_t[wave] = term; }
    __syncthreads();
    if (tid == 0) {
      float bi = 0.f, bu = 0.f, bt = 0.f;
#pragma unroll
      for (int w = 0; w < 4; ++w) { bi += s_i[w]; bu += s_u[w]; bt += s_t[w]; }
      ws[512 + j] = bi;
      ws[1536 + j] = bu;
      ws[2560 + j] = bt;
    }
  }
}

// ---------------- finalize: reduce all per-block partials ----------------
__global__ __launch_bounds__(512) void finalize_kernel(
    const float* __restrict__ ws, float* __restrict__ out, int B, int M) {
  const int tid = threadIdx.x;
  const int lane = tid & 63;
  const int wave = tid >> 6;
  __shared__ float s_e[8], s_d[8], s_r[16];

  float e = ws[tid];  // entropy partials (512)
  // boundary partials: 1024 each; thread tid takes pair (2*tid, 2*tid+1).
  // Pair shares the same image b: b = j/64 = tid/32, so threads
  // [32b, 32b+32) cover exactly image b's 64 boundary blocks.
  float inter = ws[512 + 2 * tid] + ws[512 + 2 * tid + 1];
  float uni = ws[1536 + 2 * tid] + ws[1536 + 2 * tid + 1];
  float dbc = ws[2560 + 2 * tid] + ws[2560 + 2 * tid + 1];

  for (int off = 16; off > 0; off >>= 1) {
    inter += __shfl_down(inter, off, 32);
    uni += __shfl_down(uni, off, 32);
  }
  if ((tid & 31) == 0) s_r[tid >> 5] = inter / (uni + 1e-8f);

  for (int off = 32; off > 0; off >>= 1) {
    e += __shfl_down(e, off);
    dbc += __shfl_down(dbc, off);
  }
  if (lane == 0) { s_e[wave] = e; s_d[wave] = dbc; }
  __syncthreads();

  if (tid == 0) {
    float se = 0.f, sd = 0.f, sr = 0.f;
#pragma unroll
    for (int w = 0; w < 8; ++w) { se += s_e[w]; sd += s_d[w]; }
#pragma unroll
    for (int b = 0; b < 16; ++b) sr += s_r[b];
    const float l_u = se / ((float)(B * M) + 1e-8f);
    const float l_b = 1.0f - sr / (float)B;
    const float l_d = sd / (float)((size_t)B * NPIX);
    out[0] = l_u;
    out[1] = l_b;
    out[2] = l_d;
    out[3] = 0.3f * l_u + 0.2f * l_b + 0.2f * l_d;
  }
}

extern "C" void kernel_launch(void* const* d_in, const int* in_sizes, int n_in,
                              void* d_out, int out_size, void* d_ws, size_t ws_size,
                              hipStream_t stream) {
  const int* sem = (const int*)d_in[0];        // (B, N) int32
  const float* masks = (const float*)d_in[1];  // (B, M, N) f32
  const float* depth = (const float*)d_in[2];  // (B, N) f32

  const int B = in_sizes[0] / NPIX;         // 16
  const int M = in_sizes[1] / in_sizes[0];  // 32
  float* ws = (float*)d_ws;
  float* out = (float*)d_out;

  fused_kernel<<<NB_HIST + NB_BND, 256, 0, stream>>>(masks, sem, depth, ws, M);
  finalize_kernel<<<1, 512, 0, stream>>>(ws, out, B, M);
}

// Round 8
// 204.181 us; speedup vs baseline: 1.5854x; 1.5854x over previous
//
#include <hip/hip_runtime.h>
#include <math.h>

#define NUM_CLASSES 27
#define HDIM 256
#define WDIM 256
#define NPIX (HDIM * WDIM)

// Fixed problem shape: B=16, M=32, H=W=256.
// 256-thread blocks: hist LDS = 28*256*4 = 28.7 KB -> ~5 blocks/CU (20 waves/CU)
#define NB_HIST 512              // B*M blocks, one per (b,m)
#define NB_BND 1024              // B*HDIM/4 blocks, 4 rows each (1 row/wave)
#define ROWS_PER_BND_BLOCK 4

// ws layout (floats), all slots written every launch (no zeroing needed):
//   ws[0    .. 512)  : entropy per (b,m) block
//   ws[512  .. 1536) : intersection per boundary block (1024)
//   ws[1536 .. 2560) : union per boundary block (1024)
//   ws[2560 .. 3584) : dbc-term sum per boundary block (1024)
//
// FINAL FORM — post-mortem ledger (measured, do not regress):
//  - R1 (371us) / R4-R5 (container fail) / R7 (324us): ALL fp32 LDS atomic
//    forms (atomicAdd, __hip_atomic_fetch_add WORKGROUP, unsafeAtomicAdd)
//    are catastrophic on this stack vs plain `+=` (VALUBusy ~2%, 1.6-1.8x
//    total regression). The per-thread-column `+=` RMW is the proven form;
//    the DS pipe is in-order so the write->read hazard costs nothing, and
//    8 co-resident hist waves/CU hide the read latency.
//  - R2 (243.8us): single-kernel finalize via per-block agent-scope ACQ_REL
//    fetch_add -> per-block L2 cache ops starve the memory pipe. Two-kernel
//    form keeps the free kernel-boundary release/acquire.
//  - R6 (214.2us): 4-chunk hist split -> per-block fixed costs (LDS zero-init,
//    stage-2 reduction, scheduling) exceed the latency-hiding gain.
//  - R3 (202.4us, BEST): this kernel. Remaining bench time is ~155us of
//    harness poison fills (2 x 512MiB at 86% HBM peak) + ~13-16us compulsory
//    masks stream + ~6us boundary/finalize + launch gaps. Roofline.

__global__ __launch_bounds__(256) void fused_kernel(
    const float* __restrict__ masks, const int* __restrict__ sem,
    const float* __restrict__ depth, float* __restrict__ ws, int M) {
  // Conflict-free layout: bin c of thread t at s_hist[c][t].
  // Row stride = 256 floats (== 0 mod 32 banks), so bank = t & 31:
  // class-independent, exactly 2 lanes/bank per wave access -> free (m136).
  __shared__ float s_hist[28][256];  // 28.7 KB
  __shared__ float s_part[8][32];
  __shared__ float s_i[4], s_u[4], s_t[4];

  const int tid = threadIdx.x;

  if (blockIdx.x < NB_HIST) {
    // ---------------- histogram + entropy for one (b,m) ----------------
    const int bm = blockIdx.x;
    const int b = bm / M;
    const int m = bm % M;

#pragma unroll
    for (int c = 0; c < 28; ++c) s_hist[c][tid] = 0.0f;
    // no sync needed: hot loop touches only this thread's own column

    const float4* __restrict__ m4 =
        (const float4*)(masks + ((size_t)b * M + m) * (size_t)NPIX);
    const int4* __restrict__ s4 = (const int4*)(sem + (size_t)b * (size_t)NPIX);

    const int iters = NPIX / 4 / 256;  // 64
#pragma unroll 4
    for (int it = 0; it < iters; ++it) {
      const int idx = it * 256 + tid;
      const float4 mv = m4[idx];
      const int4 cv = s4[idx];
      s_hist[cv.x][tid] += mv.x;
      s_hist[cv.y][tid] += mv.y;
      s_hist[cv.z][tid] += mv.z;
      s_hist[cv.w][tid] += mv.w;
    }
    __syncthreads();

    // stage 2: thread (c = tid&31, s = tid>>5) sums bin c over 32 columns.
    // Skew iteration by c so banks stay spread (2-way only).
    {
      const int c = tid & 31;
      const int s = tid >> 5;  // 8 groups of 32 columns
      if (c < 28) {
        float acc = 0.f;
#pragma unroll
        for (int i = 0; i < 32; ++i)
          acc += s_hist[c][s * 32 + ((i + c) & 31)];
        s_part[s][c] = acc;
      }
    }
    __syncthreads();

    // stage 3: one wave finishes
    if (tid < 64) {
      float tot = 0.f;
      if (tid < 28) {
#pragma unroll
        for (int g = 0; g < 8; ++g) tot += s_part[g][tid];
      }
      float ms = tot;  // sum of all bins == sum over n of mask
      for (int off = 32; off > 0; off >>= 1) ms += __shfl_xor(ms, off);
      ms += 1e-6f;
      float ent = 0.f;
      if (tid < NUM_CLASSES) {
        float p = fminf(fmaxf(tot / ms, 1e-7f), 1.0f);
        if (p > 1e-6f) ent = p * logf(p + 1e-10f);
      }
      for (int off = 32; off > 0; off >>= 1) ent += __shfl_xor(ent, off);
      if (tid == 0) ws[bm] = -ent;
    }
  } else {
    // ---------------- boundary IoU + depth coherence: 4 rows/block ----------------
    const int j = blockIdx.x - NB_HIST;
    const int wave = tid >> 6;
    const int lane = tid & 63;
    const int brow = j * ROWS_PER_BND_BLOCK + wave;  // all 4 rows share b
    const int b = brow >> 8;
    const int y = brow & 255;

    const size_t rowoff = (size_t)b * NPIX + (size_t)y * WDIM;
    const float4* mp = (const float4*)(masks + (size_t)b * M * NPIX + (size_t)y * WDIM);
    const float4* dp = (const float4*)(depth + rowoff);
    const int4* sp = (const int4*)(sem + rowoff);

    const int uoff = (y > 0) ? -(WDIM / 4) : 0;

    const float4 mv = mp[lane];
    const float4 mvu = mp[lane + uoff];
    const float4 dv = dp[lane];
    const float4 dvu = dp[lane + uoff];
    const int4 sv = sp[lane];
    const int4 svu = sp[lane + uoff];

    const int src = (lane > 0) ? (lane - 1) : 0;
    float mw = __shfl(mv.w, src);
    float dw = __shfl(dv.w, src);
    int swv = __shfl(sv.w, src);
    if (lane == 0) { mw = mv.x; dw = dv.x; swv = sv.x; }

    const float ml[4] = {mw, mv.x, mv.y, mv.z};
    const float dl[4] = {dw, dv.x, dv.y, dv.z};
    const int sl[4] = {swv, sv.x, sv.y, sv.z};
    const float mc[4] = {mv.x, mv.y, mv.z, mv.w};
    const float dc[4] = {dv.x, dv.y, dv.z, dv.w};
    const int sc[4] = {sv.x, sv.y, sv.z, sv.w};
    const float mu[4] = {mvu.x, mvu.y, mvu.z, mvu.w};
    const float du[4] = {dvu.x, dvu.y, dvu.z, dvu.w};
    const int su[4] = {svu.x, svu.y, svu.z, svu.w};

    float inter = 0.f, uni = 0.f, term = 0.f;
#pragma unroll
    for (int k = 0; k < 4; ++k) {
      const bool semb = (sc[k] != sl[k]) || (sc[k] != su[k]);
      const bool instb = (fabsf(mc[k] - ml[k]) > 0.3f) || (fabsf(mc[k] - mu[k]) > 0.3f);
      inter += (semb && instb) ? 1.0f : 0.0f;
      uni += (semb || instb) ? 1.0f : 0.0f;
      const float gx = dc[k] - dl[k];
      const float gy = dc[k] - du[k];
      const float db = sqrtf(fmaxf(gx * gx + gy * gy, 1e-24f));
      const float dbc = fminf(db, 2.0f);
      term += semb ? 0.0f : (1.0f + 3.0f * dbc) * dbc;
    }

    for (int off = 32; off > 0; off >>= 1) {
      inter += __shfl_down(inter, off);
      uni += __shfl_down(uni, off);
      term += __shfl_down(term, off);
    }
    if (lane == 0) { s_i[wave] = inter; s_u[wave] = uni; s_t[wave] = term; }
    __syncthreads();
    if (tid == 0) {
      float bi = 0.f, bu = 0.f, bt = 0.f;
#pragma unroll
      for (int w = 0; w < 4; ++w) { bi += s_i[w]; bu += s_u[w]; bt += s_t[w]; }
      ws[512 + j] = bi;
      ws[1536 + j] = bu;
      ws[2560 + j] = bt;
    }
  }
}

// ---------------- finalize: reduce all per-block partials ----------------
__global__ __launch_bounds__(512) void finalize_kernel(
    const float* __restrict__ ws, float* __restrict__ out, int B, int M) {
  const int tid = threadIdx.x;
  const int lane = tid & 63;
  const int wave = tid >> 6;
  __shared__ float s_e[8], s_d[8], s_r[16];

  float e = ws[tid];  // entropy partials (512)
  // boundary partials: 1024 each; thread tid takes pair (2*tid, 2*tid+1).
  // Pair shares the same image b: b = j/64 = tid/32, so threads
  // [32b, 32b+32) cover exactly image b's 64 boundary blocks.
  float inter = ws[512 + 2 * tid] + ws[512 + 2 * tid + 1];
  float uni = ws[1536 + 2 * tid] + ws[1536 + 2 * tid + 1];
  float dbc = ws[2560 + 2 * tid] + ws[2560 + 2 * tid + 1];

  for (int off = 16; off > 0; off >>= 1) {
    inter += __shfl_down(inter, off, 32);
    uni += __shfl_down(uni, off, 32);
  }
  if ((tid & 31) == 0) s_r[tid >> 5] = inter / (uni + 1e-8f);

  for (int off = 32; off > 0; off >>= 1) {
    e += __shfl_down(e, off);
    dbc += __shfl_down(dbc, off);
  }
  if (lane == 0) { s_e[wave] = e; s_d[wave] = dbc; }
  __syncthreads();

  if (tid == 0) {
    float se = 0.f, sd = 0.f, sr = 0.f;
#pragma unroll
    for (int w = 0; w < 8; ++w) { se += s_e[w]; sd += s_d[w]; }
#pragma unroll
    for (int b = 0; b < 16; ++b) sr += s_r[b];
    const float l_u = se / ((float)(B * M) + 1e-8f);
    const float l_b = 1.0f - sr / (float)B;
    const float l_d = sd / (float)((size_t)B * NPIX);
    out[0] = l_u;
    out[1] = l_b;
    out[2] = l_d;
    out[3] = 0.3f * l_u + 0.2f * l_b + 0.2f * l_d;
  }
}

extern "C" void kernel_launch(void* const* d_in, const int* in_sizes, int n_in,
                              void* d_out, int out_size, void* d_ws, size_t ws_size,
                              hipStream_t stream) {
  const int* sem = (const int*)d_in[0];        // (B, N) int32
  const float* masks = (const float*)d_in[1];  // (B, M, N) f32
  const float* depth = (const float*)d_in[2];  // (B, N) f32

  const int B = in_sizes[0] / NPIX;         // 16
  const int M = in_sizes[1] / in_sizes[0];  // 32
  float* ws = (float*)d_ws;
  float* out = (float*)d_out;

  fused_kernel<<<NB_HIST + NB_BND, 256, 0, stream>>>(masks, sem, depth, ws, M);
  finalize_kernel<<<1, 512, 0, stream>>>(ws, out, B, M);
}